// Round 1
// 93.885 us; speedup vs baseline: 1.0063x; 1.0063x over previous
//
#include <hip/hip_runtime.h>
#include <stdint.h>

typedef _Float16 half8  __attribute__((ext_vector_type(8)));
typedef float    floatx4 __attribute__((ext_vector_type(4)));
typedef uint32_t uint4v  __attribute__((ext_vector_type(4)));

#define KDIM 4096
#define ODIM 11008
#define NG   32

__device__ __forceinline__ uint32_t pk_f16(float a, float b) {
    return __builtin_bit_cast(uint32_t, __builtin_amdgcn_cvt_pkrtz(a, b));
}

// x fp32 [64][4096] -> f16 fragments xh2[g][ks][mt][lane] (uint4, halves
// slot-paired (x_j, x_{j+4})) + per-(group,m) row sums xsumT[32][64].
// (layout HW-verified R10-R14, absmax 0.125)
__global__ __launch_bounds__(256) void cvt_x_kernel(
    const float4* __restrict__ x, uint4v* __restrict__ xh2,
    float* __restrict__ xsumT)
{
    const int i = blockIdx.x * 256 + threadIdx.x;
    const float4 f0 = x[2 * i];
    const float4 f1 = x[2 * i + 1];
    const uint4v v = {pk_f16(f0.x, f1.x), pk_f16(f0.y, f1.y),
                      pk_f16(f0.z, f1.z), pk_f16(f0.w, f1.w)};
    const int m  = i >> 9, c = i & 511;
    const int g  = c >> 4, cg = c & 15, q = cg >> 2, ks = cg & 3;
    const int mt = m >> 4, ml = m & 15;
    xh2[((size_t)(g * 4 + ks) * 4 + mt) * 64 + q * 16 + ml] = v;

    float p = f0.x + f0.y + f0.z + f0.w + f1.x + f1.y + f1.z + f1.w;
    p += __shfl_xor(p, 1);
    p += __shfl_xor(p, 2);
    p += __shfl_xor(p, 4);
    p += __shfl_xor(p, 8);
    if ((threadIdx.x & 15) == 0) xsumT[g * 64 + m] = p;
}

// Block: 32 o-cols x FULL K; 4 waves = 4 k-quarters, each covering all 64 m
// (4 M-tiles) and BOTH o-halves (o, o+16) -> each ax[8] x-fragment burst now
// feeds 2 B-fragments, halving xh2 L2 traffic (344 MB -> 172 MB) vs the
// 16-col tile. Grid 344 = fully co-resident at 2 blocks/CU (no 176-block
// tail). qweight: distance-2 circular prefetch per o-half, NO main-loop
// barriers. g-loop ROLLED (#pragma unroll 1) to bound live ranges
// (anti-spill; lesson of R11/R13/R14). Epilogue: 32-KB LDS k-reduce +
// direct stores.
__global__ __launch_bounds__(256, 2) void w4a16_kernel(
    const uint4v*   __restrict__ xh2,    // [32][4][4][64] uint4
    const uint4v*   __restrict__ qw,     // [11008][128] uint4
    const uint32_t* __restrict__ qz,     // [11008][4]
    const float*    __restrict__ sc,     // [11008][32] (fp32-upcast fp16)
    const float*    __restrict__ xsumT,  // [32][64]
    float*          __restrict__ out)    // [64][11008]
{
    __shared__ float red[4][2][16][64];  // 32 KB

    const int t    = threadIdx.x;
    const int kw   = t >> 6;            // wave -> k-quarter (groups kw*8..+7)
    const int lane = t & 63;
    const int q    = lane >> 4;
    const int ml   = lane & 15;

    const int o0 = blockIdx.x * 32;
    const int oa = o0 + ml;             // B col (half A) = ml
    const int ob = o0 + 16 + ml;        // B col (half B)
    const int g0 = kw * 8;

    const uint4v* qwpa = qw + (size_t)oa * 128 + g0 * 4 + q;
    const uint4v* qwpb = qw + (size_t)ob * 128 + g0 * 4 + q;
    const uint32_t zdwa = qz[(size_t)oa * 4 + kw];    // 8 nibbles = 8 groups
    const uint32_t zdwb = qz[(size_t)ob * 4 + kw];
    const floatx4 sva0 = *reinterpret_cast<const floatx4*>(sc + (size_t)oa * NG + g0);
    const floatx4 sva1 = *reinterpret_cast<const floatx4*>(sc + (size_t)oa * NG + g0 + 4);
    const floatx4 svb0 = *reinterpret_cast<const floatx4*>(sc + (size_t)ob * NG + g0);
    const floatx4 svb1 = *reinterpret_cast<const floatx4*>(sc + (size_t)ob * NG + g0 + 4);

    const uint4v* xp = xh2 + (size_t)g0 * 1024 + lane;   // + (gl*16 + i)*64
    const float*  xs = xsumT + (size_t)g0 * 64 + q * 4;  // + gl*64 + mt*16

    floatx4 accA[4] = {{0.f,0.f,0.f,0.f},{0.f,0.f,0.f,0.f},
                       {0.f,0.f,0.f,0.f},{0.f,0.f,0.f,0.f}};
    floatx4 accB[4] = {{0.f,0.f,0.f,0.f},{0.f,0.f,0.f,0.f},
                       {0.f,0.f,0.f,0.f},{0.f,0.f,0.f,0.f}};

    // distance-2 circular qweight prefetch, per o-half (16 VGPR)
    uint4v ubufA[2], ubufB[2];
    ubufA[0] = qwpa[0];  ubufB[0] = qwpb[0];
    ubufA[1] = qwpa[4];  ubufB[1] = qwpb[4];

    #pragma unroll 1
    for (int gl = 0; gl < 8; ++gl) {
        const uint4v ucA = ubufA[gl & 1];
        const uint4v ucB = ubufB[gl & 1];
        if (gl + 2 < 8) {
            ubufA[gl & 1] = qwpa[(gl + 2) * 4];
            ubufB[gl & 1] = qwpb[(gl + 2) * 4];
        }

        const uint32_t zna = (zdwa >> (gl * 4)) & 0xFu;
        const uint32_t znb = (zdwb >> (gl * 4)) & 0xFu;
        const float    sa  = (gl < 4) ? sva0[gl] : sva1[gl - 4];
        const float    sb  = (gl < 4) ? svb0[gl] : svb1[gl - 4];
        const float    czsa = sa * (1024.0f + (float)zna);
        const float    czsb = sb * (1024.0f + (float)znb);

        floatx4 tA[4] = {{0.f,0.f,0.f,0.f},{0.f,0.f,0.f,0.f},
                         {0.f,0.f,0.f,0.f},{0.f,0.f,0.f,0.f}};
        floatx4 tB[4] = {{0.f,0.f,0.f,0.f},{0.f,0.f,0.f,0.f},
                         {0.f,0.f,0.f,0.f},{0.f,0.f,0.f,0.f}};

        #pragma unroll
        for (int h = 0; h < 2; ++h) {           // half-group: ks = 2h, 2h+1
            // batched 8-load MLP burst (32 VGPR live) -- shared by o-halves
            uint4v ax[8];
            #pragma unroll
            for (int i = 0; i < 8; ++i)
                ax[i] = xp[(size_t)(gl * 16 + h * 8 + i) * 64];

            #pragma unroll
            for (int k2 = 0; k2 < 2; ++k2) {
                const int ks = h * 2 + k2;
                const uint32_t udA = ucA[ks];
                const uint32_t udB = ucB[ks];
                const uint4v bwA = {
                    ( udA         & 0x000F000Fu) | 0x64006400u,
                    ((udA >> 4)   & 0x000F000Fu) | 0x64006400u,
                    ((udA >> 8)   & 0x000F000Fu) | 0x64006400u,
                    ((udA >> 12)  & 0x000F000Fu) | 0x64006400u};
                const uint4v bwB = {
                    ( udB         & 0x000F000Fu) | 0x64006400u,
                    ((udB >> 4)   & 0x000F000Fu) | 0x64006400u,
                    ((udB >> 8)   & 0x000F000Fu) | 0x64006400u,
                    ((udB >> 12)  & 0x000F000Fu) | 0x64006400u};
                const half8 bA = __builtin_bit_cast(half8, bwA);
                const half8 bB = __builtin_bit_cast(half8, bwB);
                #pragma unroll
                for (int mt = 0; mt < 4; ++mt) {
                    const half8 a = __builtin_bit_cast(half8, ax[k2 * 4 + mt]);
                    tA[mt] = __builtin_amdgcn_mfma_f32_16x16x32_f16(
                        a, bA, tA[mt], 0, 0, 0);
                    tB[mt] = __builtin_amdgcn_mfma_f32_16x16x32_f16(
                        a, bB, tB[mt], 0, 0, 0);
                }
            }
        }

        // scale + zero-point correction (xsumT is L1-resident, 8 KB)
        #pragma unroll
        for (int mt = 0; mt < 4; ++mt) {
            const floatx4 xg = *reinterpret_cast<const floatx4*>(
                xs + gl * 64 + mt * 16);
            #pragma unroll
            for (int r = 0; r < 4; ++r) {
                accA[mt][r] += sa * tA[mt][r] - czsa * xg[r];
                accB[mt][r] += sb * tB[mt][r] - czsb * xg[r];
            }
        }
    }

    // cross-wave k-reduce through LDS, then direct final stores (R12-verified
    // pattern, widened to 2 o-halves)
    #pragma unroll
    for (int mt = 0; mt < 4; ++mt)
        #pragma unroll
        for (int r = 0; r < 4; ++r) {
            red[kw][0][mt * 4 + r][lane] = accA[mt][r];
            red[kw][1][mt * 4 + r][lane] = accB[mt][r];
        }
    __syncthreads();

    const int mt2 = t >> 6;             // reuse wave id as output M-tile
    #pragma unroll
    for (int oc = 0; oc < 2; ++oc)
        #pragma unroll
        for (int r = 0; r < 4; ++r) {
            const int i = mt2 * 4 + r;
            const float sum = red[0][oc][i][lane] + red[1][oc][i][lane]
                            + red[2][oc][i][lane] + red[3][oc][i][lane];
            out[(size_t)(mt2 * 16 + q * 4 + r) * ODIM + o0 + oc * 16 + ml] = sum;
        }
}

extern "C" void kernel_launch(void* const* d_in, const int* in_sizes, int n_in,
                              void* d_out, int out_size, void* d_ws, size_t ws_size,
                              hipStream_t stream) {
    const float*    x       = (const float*)d_in[0];
    const uint32_t* qweight = (const uint32_t*)d_in[1];
    const uint32_t* qzeros  = (const uint32_t*)d_in[2];
    const float*    scales  = (const float*)d_in[3];
    float* out = (float*)d_out;

    uint4v* xh2   = (uint4v*)d_ws;                         // 512 KB
    float*  xsumT = (float*)((char*)d_ws + 512 * 1024);    // 8 KB

    cvt_x_kernel<<<dim3(128), dim3(256), 0, stream>>>((const float4*)x, xh2, xsumT);
    w4a16_kernel<<<dim3(ODIM / 32), dim3(256), 0, stream>>>(
        xh2, (const uint4v*)qweight, qzeros, scales, xsumT, out);
}